// Round 15
// baseline (69.219 us; speedup 1.0000x reference)
//
#include <hip/hip_runtime.h>

// SparseSelfAttention, algebraically reduced:
//   out[hd] = sum_g c_g * softmax(Q_hd K_g^T / 16) @ Vs[(2hd-g)%4]
//   Vs[head][j] = sum_{w=-2..2} v[head][(j+2w)%N]
//   c_g = 2 if (hd-g)%4==2 else 1
// N=2304 tokens, 4 heads, dh=64.
//
// R15: KERNEL-COUNT reduction. Smoothing commutes with the linear projection:
//   Vs = xs @ Wv^T + 5*bv,  xs[n] = sum_t x[(n+t)%N], t in {-4,-2,0,2,4}
// so k_proj's mat-2 blocks read the 5 shifted x-windows (all in-block) and
// emit smoothed V directly in fragment-major k-slot-permuted VF layout via an
// LDS-staged epilogue. k_smooth and VfT are GONE: 3 kernels total. The ~25us
// that never responded to k_flash/producer changes (R10/R12/R13/R14 nulls) is
// attributed to kernel-count + inter-kernel gaps.
// k_flash = R10-proven body. R12: split-K x8 regressed. R11: V-direct
// regressed. R6: VGPR<128. R5: no waves/EU clamp. R8: cvt_pkrtz is __fp16.

#define N_TOK 2304
#define OUTC 256
#define HSZ (N_TOK * 64)   // halfs per head = 147456

typedef _Float16 half8 __attribute__((ext_vector_type(8)));
typedef _Float16 half4 __attribute__((ext_vector_type(4)));
typedef __fp16 fp16x2 __attribute__((ext_vector_type(2)));
typedef float f32x4 __attribute__((ext_vector_type(4)));

typedef __attribute__((address_space(3))) unsigned int as3_u32;
typedef __attribute__((address_space(1))) unsigned int as1_u32;

__device__ __forceinline__ f32x4 mfma16(half8 a, half8 b, f32x4 c) {
  return __builtin_amdgcn_mfma_f32_16x16x32_f16(a, b, c, 0, 0, 0);
}

__device__ __forceinline__ void gload_lds16(const _Float16* g, _Float16* l) {
  __builtin_amdgcn_global_load_lds((const as1_u32*)g, (as3_u32*)l, 16, 0, 0);
}

union H8U { half8 h8; fp16x2 h2[4]; };

__device__ __forceinline__ half8 pack_f32x8(const float* e) {
  H8U u;
  u.h2[0] = __builtin_amdgcn_cvt_pkrtz(e[0], e[1]);
  u.h2[1] = __builtin_amdgcn_cvt_pkrtz(e[2], e[3]);
  u.h2[2] = __builtin_amdgcn_cvt_pkrtz(e[4], e[5]);
  u.h2[3] = __builtin_amdgcn_cvt_pkrtz(e[6], e[7]);
  return u.h8;
}

// ---- kernel 1: QKV projection (f32 in, LDS-staged coalesced epilogues) ----
// mat 0 -> Qh[hd][n][d] row-major, scaled log2(e)/16
// mat 1 -> KF fragment-major: block (bx,hd) owns KF[hd*HSZ + bx*4096 ..+4096)
// mat 2 -> VF fragment-major SMOOTHED: A-operand is xs (5-shift sum of x),
//          bias 5*bv; block (bx,vh) owns VF[vh*HSZ + bx*4096 ..+4096)
__global__ __launch_bounds__(256) void k_proj(
    const float* __restrict__ x, const float* __restrict__ Wq,
    const float* __restrict__ Wk, const float* __restrict__ Wv,
    const float* __restrict__ bq, const float* __restrict__ bk,
    const float* __restrict__ bv,
    _Float16* __restrict__ Qh, _Float16* __restrict__ KF, _Float16* __restrict__ VF) {
  __shared__ _Float16 stg[4096];
  const int w = threadIdx.x >> 6, lane = threadIdx.x & 63;
  const int lr = lane & 15, lk = lane >> 4;
  const int n0 = blockIdx.x * 64 + w * 16;
  const int o0 = blockIdx.y * 64;
  const int mat = blockIdx.z;
  const float* W = (mat == 0) ? Wq : (mat == 1) ? Wk : Wv;
  f32x4 acc[4] = {};

  if (mat == 2) {
    // A = xs rows (smoothed), 5 shifted row pointers with wraparound
    const float* rp[5];
#pragma unroll
    for (int u = 0; u < 5; ++u) {
      int row = n0 + lr + 2*u - 4;
      row = (row + N_TOK) % N_TOK;
      rp[u] = x + (size_t)row * OUTC + 8 * lk;
    }
#pragma unroll
    for (int kk = 0; kk < 8; ++kk) {
      float af[8] = {};
#pragma unroll
      for (int u = 0; u < 5; ++u) {
        float4 p0 = *(const float4*)(rp[u] + 32 * kk);
        float4 p1 = *(const float4*)(rp[u] + 32 * kk + 4);
        af[0] += p0.x; af[1] += p0.y; af[2] += p0.z; af[3] += p0.w;
        af[4] += p1.x; af[5] += p1.y; af[6] += p1.z; af[7] += p1.w;
      }
      half8 a = pack_f32x8(af);
#pragma unroll
      for (int c = 0; c < 4; ++c) {
        const float* wrow = W + (size_t)(o0 + 16*c + lr) * OUTC + 32*kk + 8*lk;
        float bf[8];
        *(float4*)&bf[0] = *(const float4*)(wrow);
        *(float4*)&bf[4] = *(const float4*)(wrow + 4);
        half8 b = pack_f32x8(bf);
        acc[c] = mfma16(a, b, acc[c]);
      }
    }
    // stage fragment-major + k-slot-permuted:
    //   f = c*128 + (w>>1)*64 + lk*16 + lr,  i = 4*(w&1) + r
#pragma unroll
    for (int c = 0; c < 4; ++c) {
      float bo = 5.0f * bv[o0 + 16*c + lr];
#pragma unroll
      for (int r = 0; r < 4; ++r)
        stg[(c*128 + (w>>1)*64 + lk*16 + lr)*8 + 4*(w&1) + r] =
            (_Float16)(acc[c][r] + bo);
    }
    __syncthreads();
    _Float16* dst = VF + (size_t)blockIdx.y * HSZ + (size_t)blockIdx.x * 4096;
    ((half8*)dst)[threadIdx.x]       = ((const half8*)stg)[threadIdx.x];
    ((half8*)dst)[256 + threadIdx.x] = ((const half8*)stg)[256 + threadIdx.x];
    return;
  }

  const float* xrow = x + (size_t)(n0 + lr) * OUTC + 8 * lk;
#pragma unroll
  for (int kk = 0; kk < 8; ++kk) {
    float af[8];
    *(float4*)&af[0] = *(const float4*)(xrow + 32 * kk);
    *(float4*)&af[4] = *(const float4*)(xrow + 32 * kk + 4);
    half8 a = pack_f32x8(af);
#pragma unroll
    for (int c = 0; c < 4; ++c) {
      const float* wrow = W + (size_t)(o0 + 16*c + lr) * OUTC + 32*kk + 8*lk;
      float bf[8];
      *(float4*)&bf[0] = *(const float4*)(wrow);
      *(float4*)&bf[4] = *(const float4*)(wrow + 4);
      half8 b = pack_f32x8(bf);
      acc[c] = mfma16(a, b, acc[c]);
    }
  }
  const float* bias = (mat == 0) ? bq : bk;
  const int hd = blockIdx.y;

  if (mat == 0) {
    const float qs = 0.0625f * 1.4426950408889634f;   // (1/16) * log2(e)
#pragma unroll
    for (int c = 0; c < 4; ++c) {
      float bo = bias[o0 + 16*c + lr];
      int d = 16*c + lr;
#pragma unroll
      for (int r = 0; r < 4; ++r)
        stg[(w*16 + 4*lk + r) * 64 + d] = (_Float16)((acc[c][r] + bo) * qs);
    }
    __syncthreads();
    _Float16* dst = Qh + ((size_t)hd * N_TOK + blockIdx.x * 64) * 64;
    ((half8*)dst)[threadIdx.x]       = ((const half8*)stg)[threadIdx.x];
    ((half8*)dst)[256 + threadIdx.x] = ((const half8*)stg)[256 + threadIdx.x];
  } else {
    // KF local idx = (w*2+h)*512 + (g4K*16 + 4*lk + r)*8 + iiK  (cK == w)
#pragma unroll
    for (int c = 0; c < 4; ++c) {
      float bo = bias[o0 + 16*c + lr];
      int d = 16*c + lr;
      int h = d >> 5, g4K = (d >> 3) & 3, iiK = d & 7;
#pragma unroll
      for (int r = 0; r < 4; ++r)
        stg[(w*2 + h)*512 + (g4K*16 + 4*lk + r)*8 + iiK] = (_Float16)(acc[c][r] + bo);
    }
    __syncthreads();
    _Float16* dst = KF + (size_t)hd * HSZ + (size_t)blockIdx.x * 4096;
    ((half8*)dst)[threadIdx.x]       = ((const half8*)stg)[threadIdx.x];
    ((half8*)dst)[256 + threadIdx.x] = ((const half8*)stg)[256 + threadIdx.x];
  }
}

// ---- kernel 2: flash attention (R10-proven), LDS tiles, counted vmcnt ----
__global__ __launch_bounds__(256) void k_flash(
    const _Float16* __restrict__ Qh, const _Float16* __restrict__ KF,
    const _Float16* __restrict__ VF,
    _Float16* __restrict__ Opart, float* __restrict__ Lpart) {
  __shared__ __align__(16) _Float16 lds[2][8192];   // [buf][ K:0..4095 | V:4096..8191 ]
  const int wv = threadIdx.x >> 6, lane = threadIdx.x & 63;
  const int lr = lane & 15, g4 = lane >> 4;
  const int strip = blockIdx.x * 4 + wv;      // 0..71, 32 queries each
  const int n0 = strip * 32;
  const int pair = blockIdx.y;                // hd*4 + gk
  const int hd = pair >> 2, gk = pair & 3;
  const int chunk = blockIdx.z;               // 9 tiles each
  const int vh = (2*hd + 4 - gk) & 3;

  const _Float16* Qp = Qh + ((size_t)hd * N_TOK + n0 + lr) * 64 + 8*g4;
  const half8 qa0 = *(const half8*)(Qp);
  const half8 qa1 = *(const half8*)(Qp + 32);
  const half8 qb0 = *(const half8*)(Qp + 16*64);
  const half8 qb1 = *(const half8*)(Qp + 16*64 + 32);

  const _Float16* Kt = KF + (size_t)gk * HSZ + (size_t)chunk * 9 * 4096;
  const _Float16* Vt = VF + (size_t)vh * HSZ + (size_t)chunk * 9 * 4096;
  const _Float16* gsrc = (wv < 2 ? Kt : Vt) + (wv & 1) * 2048 + lane * 8;
  const int ldsoff = (wv < 2 ? 0 : 4096) + (wv & 1) * 2048;

  f32x4 accA[4] = {}, accB[4] = {};
  f32x4 acclA = {}, acclB = {};
  half8 ones;
#pragma unroll
  for (int i = 0; i < 8; ++i) ones[i] = (_Float16)1.0f;

  auto stage = [&](int t, int b) {
    const _Float16* s = gsrc + (size_t)t * 4096;
    _Float16* d = &lds[b][ldsoff];
    gload_lds16(s,        d);
    gload_lds16(s + 512,  d + 512);
    gload_lds16(s + 1024, d + 1024);
    gload_lds16(s + 1536, d + 1536);
  };
  auto body = [&](int b) {
    const _Float16* ldsK = &lds[b][0]    + lane * 8;
    const _Float16* ldsV = &lds[b][4096] + lane * 8;
    f32x4 sA[4], sB[4];
    __builtin_amdgcn_s_setprio(1);
#pragma unroll
    for (int c = 0; c < 4; ++c) {
      half8 k0 = *(const half8*)(ldsK + c*1024);
      half8 k1 = *(const half8*)(ldsK + c*1024 + 512);
      f32x4 tA = {}; tA = mfma16(k0, qa0, tA); tA = mfma16(k1, qa1, tA); sA[c] = tA;
      f32x4 tB = {}; tB = mfma16(k0, qb0, tB); tB = mfma16(k1, qb1, tB); sB[c] = tB;
    }
    __builtin_amdgcn_s_setprio(0);
    H8U a0, a1, b0, b1;
#pragma unroll
    for (int c = 0; c < 4; ++c) {
      float eA0 = __builtin_amdgcn_exp2f(sA[c][0]);
      float eA1 = __builtin_amdgcn_exp2f(sA[c][1]);
      float eA2 = __builtin_amdgcn_exp2f(sA[c][2]);
      float eA3 = __builtin_amdgcn_exp2f(sA[c][3]);
      float eB0 = __builtin_amdgcn_exp2f(sB[c][0]);
      float eB1 = __builtin_amdgcn_exp2f(sB[c][1]);
      float eB2 = __builtin_amdgcn_exp2f(sB[c][2]);
      float eB3 = __builtin_amdgcn_exp2f(sB[c][3]);
      H8U* da = (c < 2) ? &a0 : &a1;
      H8U* db = (c < 2) ? &b0 : &b1;
      int base = (c & 1) * 2;
      da->h2[base]     = __builtin_amdgcn_cvt_pkrtz(eA0, eA1);
      da->h2[base + 1] = __builtin_amdgcn_cvt_pkrtz(eA2, eA3);
      db->h2[base]     = __builtin_amdgcn_cvt_pkrtz(eB0, eB1);
      db->h2[base + 1] = __builtin_amdgcn_cvt_pkrtz(eB2, eB3);
    }
    __builtin_amdgcn_s_setprio(1);
#pragma unroll
    for (int cc = 0; cc < 4; ++cc) {
      half8 v0 = *(const half8*)(ldsV + cc*1024);
      half8 v1 = *(const half8*)(ldsV + cc*1024 + 512);
      accA[cc] = mfma16(v0, a0.h8, accA[cc]); accA[cc] = mfma16(v1, a1.h8, accA[cc]);
      accB[cc] = mfma16(v0, b0.h8, accB[cc]); accB[cc] = mfma16(v1, b1.h8, accB[cc]);
    }
    acclA = mfma16(ones, a0.h8, acclA); acclA = mfma16(ones, a1.h8, acclA);
    acclB = mfma16(ones, b0.h8, acclB); acclB = mfma16(ones, b1.h8, acclB);
    __builtin_amdgcn_s_setprio(0);
  };

  stage(0, 0);
#pragma unroll 1
  for (int t = 0; t < 9; ++t) {
    if (t < 8) {
      stage(t + 1, (t + 1) & 1);                       // 4 loads in flight
      asm volatile("s_waitcnt vmcnt(4)" ::: "memory"); // own stage(t) landed
    } else {
      asm volatile("s_waitcnt vmcnt(0)" ::: "memory");
    }
    __builtin_amdgcn_sched_barrier(0);
    __builtin_amdgcn_s_barrier();        // all waves' stage(t) landed
    __builtin_amdgcn_sched_barrier(0);
    body(t & 1);
    if (t < 8) {
      __builtin_amdgcn_sched_barrier(0);
      __builtin_amdgcn_s_barrier();      // all readers of buf done before overwrite
    }
  }

  float invA = 1.0f / acclA[0];
  float invB = 1.0f / acclB[0];
  _Float16* Oa = Opart + (((size_t)chunk * 16 + pair) * N_TOK + n0 + lr) * 64;
  _Float16* Ob = Oa + 16 * 64;
#pragma unroll
  for (int cc = 0; cc < 4; ++cc) {
    half4 ha, hb;
#pragma unroll
    for (int r = 0; r < 4; ++r) {
      ha[r] = (_Float16)(accA[cc][r] * invA);
      hb[r] = (_Float16)(accB[cc][r] * invB);
    }
    *(half4*)(Oa + 16*cc + 4*g4) = ha;
    *(half4*)(Ob + 16*cc + 4*g4) = hb;
  }
  if (g4 == 0) {
    Lpart[((size_t)chunk * 16 + pair) * N_TOK + n0 + lr] = acclA[0];
    Lpart[((size_t)chunk * 16 + pair) * N_TOK + n0 + 16 + lr] = acclB[0];
  }
}

// ---- kernel 3: merge split-K chunks (l-weighted), weight by c_g, sum over gk ----
__global__ __launch_bounds__(256) void k_combine(
    const _Float16* __restrict__ Opart, const float* __restrict__ Lpart,
    float* __restrict__ out) {
  int gid = blockIdx.x * 256 + threadIdx.x;   // 73728 total
  int hd = gid / (N_TOK * 8);
  int rem = gid % (N_TOK * 8);
  int n = rem >> 3, db = (rem & 7) * 8;
  float acc[8] = {};
#pragma unroll
  for (int gk = 0; gk < 4; ++gk) {
    float cg = (((hd - gk) & 3) == 2) ? 2.0f : 1.0f;
    int pair = hd * 4 + gk;
    float la[4], lsum = 0.f;
#pragma unroll
    for (int ch = 0; ch < 4; ++ch) {
      la[ch] = Lpart[((size_t)ch * 16 + pair) * N_TOK + n];
      lsum += la[ch];
    }
    float rs = cg / lsum;
#pragma unroll
    for (int ch = 0; ch < 4; ++ch) {
      half8 v = *(const half8*)(Opart + (((size_t)ch * 16 + pair) * N_TOK + n) * 64 + db);
      float w = la[ch] * rs;
#pragma unroll
      for (int i = 0; i < 8; ++i) acc[i] += w * (float)v[i];
    }
  }
  float* dst = out + (size_t)n * OUTC + hd * 64 + db;
  float4 r0, r1;
  r0.x = acc[0]; r0.y = acc[1]; r0.z = acc[2]; r0.w = acc[3];
  r1.x = acc[4]; r1.y = acc[5]; r1.z = acc[6]; r1.w = acc[7];
  *(float4*)(dst)     = r0;
  *(float4*)(dst + 4) = r1;
}

extern "C" void kernel_launch(void* const* d_in, const int* in_sizes, int n_in,
                              void* d_out, int out_size, void* d_ws, size_t ws_size,
                              hipStream_t stream) {
  (void)in_sizes; (void)n_in; (void)out_size; (void)ws_size;
  const float* x  = (const float*)d_in[0];
  const float* Wq = (const float*)d_in[1];
  const float* bq = (const float*)d_in[2];
  const float* Wk = (const float*)d_in[3];
  const float* bk = (const float*)d_in[4];
  const float* Wv = (const float*)d_in[5];
  const float* bv = (const float*)d_in[6];

  char* ws = (char*)d_ws;
  float*    Lp  = (float*)   (ws);              //   589,824 B
  _Float16* Qh  = (_Float16*)(ws + 1179648);    // 1,179,648 B
  _Float16* KF  = (_Float16*)(ws + 2359296);    // 1,179,648 B (fragment-major)
  _Float16* VF  = (_Float16*)(ws + 3538944);    // 1,179,648 B (fragment-major, smoothed)
  _Float16* Op  = (_Float16*)(ws + 4718592);    // 18,874,368 B (ends 23,592,960 -- proven range)
  float* out = (float*)d_out;

  k_proj   <<<dim3(36, 4, 3), dim3(256), 0, stream>>>(x, Wq, Wk, Wv, bq, bk, bv, Qh, KF, VF);
  k_flash  <<<dim3(18, 16, 4), dim3(256), 0, stream>>>(Qh, KF, VF, Op, Lp);
  k_combine<<<dim3(288), dim3(256), 0, stream>>>(Op, Lp, out);
}